// Round 7
// baseline (422.567 us; speedup 1.0000x reference)
//
#include <hip/hip_runtime.h>

// Problem constants (fixed by the reference)
#define NHEADS 8
#define NKVH   2
#define HD     256
#define SEQ    4096
#define HID    2048
#define QKVN   3072   // (NH + 2*NKV) * D
#define SCAL   (1.0f/256.0f)

typedef __attribute__((ext_vector_type(8))) __bf16 bf16x8;
typedef __attribute__((ext_vector_type(4))) float  f32x4;

__device__ __forceinline__ unsigned short f2bf(float f) {
  unsigned int u = __builtin_bit_cast(unsigned int, f);
  u += 0x7fffu + ((u >> 16) & 1u);          // round-to-nearest-even
  return (unsigned short)(u >> 16);
}
__device__ __forceinline__ float bf2f(unsigned short b) {
  return __builtin_bit_cast(float, (unsigned int)b << 16);
}

// async global->LDS, 16B per lane (linear LDS dest = wave base + lane*16)
__device__ __forceinline__ void async_copy16(const void* g, void* l) {
  __builtin_amdgcn_global_load_lds(
      (__attribute__((address_space(1))) void*)(g),
      (__attribute__((address_space(3))) void*)(l), 16, 0, 0);
}

// ---------------------------------------------------------------- fp32->bf16
__global__ __launch_bounds__(256) void cvt_bf16(const float* __restrict__ in,
                                                unsigned short* __restrict__ out,
                                                int n4) {
  int i = blockIdx.x * 256 + threadIdx.x;
  if (i >= n4) return;
  float4 v = reinterpret_cast<const float4*>(in)[i];
  ushort4 o;
  o.x = f2bf(v.x); o.y = f2bf(v.y); o.z = f2bf(v.z); o.w = f2bf(v.w);
  reinterpret_cast<ushort4*>(out)[i] = o;
}

// ------------------------------------------------------- C = A(M,K) * B(N,K)^T
// 128x128 tile, BK=64, 4 waves as 2x2 of 64x64.  (verified rounds 1-6)
template <bool OUT_BF16>
__global__ __launch_bounds__(256) void gemm_bt(const unsigned short* __restrict__ A,
                                               const unsigned short* __restrict__ B,
                                               void* __restrict__ C,
                                               int M, int N, int K) {
  __shared__ __align__(16) unsigned short Als[128 * 64];
  __shared__ __align__(16) unsigned short Bls[128 * 64];
  const int t    = threadIdx.x;
  const int lane = t & 63;
  const int wid  = t >> 6;
  const int wr = wid >> 1, wc = wid & 1;
  const int l15 = lane & 15, lg = lane >> 4;
  const int m0 = blockIdx.y * 128, n0 = blockIdx.x * 128;

  f32x4 acc[4][4] = {};

  for (int k0 = 0; k0 < K; k0 += 64) {
    __syncthreads();                                  // LDS reuse fence
#pragma unroll
    for (int i = 0; i < 4; ++i) {
      int c   = i * 256 + t;                          // 16B chunk index 0..1023
      int kc  = c >> 9;
      int row = (c >> 2) & 127;
      int j8  = (c & 3) ^ (row & 3);                  // inverse-swizzled source
      int gcol = k0 + kc * 32 + j8 * 8;
      async_copy16(A + (size_t)(m0 + row) * K + gcol, Als + c * 8);
      async_copy16(B + (size_t)(n0 + row) * K + gcol, Bls + c * 8);
    }
    __syncthreads();                                  // drains vmcnt before use
#pragma unroll
    for (int kc = 0; kc < 2; ++kc) {
      bf16x8 af[4], bfr[4];
#pragma unroll
      for (int m = 0; m < 4; ++m) {
        int row   = wr * 64 + m * 16 + l15;
        int chunk = kc * 512 + row * 4 + (lg ^ (row & 3));
        af[m] = *reinterpret_cast<const bf16x8*>(Als + chunk * 8);
      }
#pragma unroll
      for (int n = 0; n < 4; ++n) {
        int row   = wc * 64 + n * 16 + l15;
        int chunk = kc * 512 + row * 4 + (lg ^ (row & 3));
        bfr[n] = *reinterpret_cast<const bf16x8*>(Bls + chunk * 8);
      }
#pragma unroll
      for (int m = 0; m < 4; ++m)
#pragma unroll
        for (int n = 0; n < 4; ++n)
          acc[m][n] = __builtin_amdgcn_mfma_f32_16x16x32_bf16(af[m], bfr[n],
                                                              acc[m][n], 0, 0, 0);
    }
  }

#pragma unroll
  for (int m = 0; m < 4; ++m) {
#pragma unroll
    for (int n = 0; n < 4; ++n) {
      int col = n0 + wc * 64 + n * 16 + l15;
#pragma unroll
      for (int r = 0; r < 4; ++r) {
        int rowg = m0 + wr * 64 + m * 16 + lg * 4 + r;   // C/D: row=(l>>4)*4+r
        if constexpr (OUT_BF16)
          reinterpret_cast<unsigned short*>(C)[(size_t)rowg * N + col] =
              f2bf(acc[m][n][r]);
        else
          reinterpret_cast<float*>(C)[(size_t)rowg * N + col] = acc[m][n][r];
      }
    }
  }
}

// --------------------------------------------- RMSNorm + RoPE + layout split
__global__ __launch_bounds__(256) void postproc(const unsigned short* __restrict__ qkv,
                                                const float* __restrict__ cosb,
                                                const float* __restrict__ sinb,
                                                unsigned short* __restrict__ q,
                                                unsigned short* __restrict__ k,
                                                unsigned short* __restrict__ vt) {
  const int wid = threadIdx.x >> 6, lane = threadIdx.x & 63;
  const int task = blockIdx.x * 4 + wid;          // 0 .. SEQ*12-1
  const int s = task / 12, comp = task % 12;

  ushort4 raw = reinterpret_cast<const ushort4*>(qkv + (size_t)task * 256)[lane];
  float x0 = bf2f(raw.x), x1 = bf2f(raw.y), x2 = bf2f(raw.z), x3 = bf2f(raw.w);

  float ss = x0 * x0 + x1 * x1 + x2 * x2 + x3 * x3;
#pragma unroll
  for (int m = 1; m < 64; m <<= 1) ss += __shfl_xor(ss, m);
  float inv = rsqrtf(ss * (1.0f / 256.0f) + 1e-6f);
  x0 *= inv; x1 *= inv; x2 *= inv; x3 *= inv;

  if (comp < 10) {  // RoPE: lane d-range 4*lane..4*lane+3, partner ±128
    float4 c  = reinterpret_cast<const float4*>(cosb + (size_t)s * 256)[lane];
    float4 sn = reinterpret_cast<const float4*>(sinb + (size_t)s * 256)[lane];
    float p0 = __shfl_xor(x0, 32), p1 = __shfl_xor(x1, 32);
    float p2 = __shfl_xor(x2, 32), p3 = __shfl_xor(x3, 32);
    float sg = (lane < 32) ? -1.0f : 1.0f;       // rotate_half sign
    x0 = x0 * c.x + sg * p0 * sn.x;
    x1 = x1 * c.y + sg * p1 * sn.y;
    x2 = x2 * c.z + sg * p2 * sn.z;
    x3 = x3 * c.w + sg * p3 * sn.w;
  }

  if (comp < 8) {
    ushort4 o;
    o.x = f2bf(x0 * SCAL); o.y = f2bf(x1 * SCAL);
    o.z = f2bf(x2 * SCAL); o.w = f2bf(x3 * SCAL);
    reinterpret_cast<ushort4*>(q + ((size_t)s * NHEADS + comp) * 256)[lane] = o;
  } else if (comp < 10) {
    ushort4 o;
    o.x = f2bf(x0); o.y = f2bf(x1); o.z = f2bf(x2); o.w = f2bf(x3);
    reinterpret_cast<ushort4*>(k + ((size_t)(comp - 8) * SEQ + s) * 256)[lane] = o;
  } else {  // v -> V^T[kvh][d][s]
    size_t base = (size_t)(comp - 10) * 256 * SEQ + s;
    int d0 = lane * 4;
    vt[base + (size_t)(d0 + 0) * SEQ] = f2bf(x0);
    vt[base + (size_t)(d0 + 1) * SEQ] = f2bf(x1);
    vt[base + (size_t)(d0 + 2) * SEQ] = f2bf(x2);
    vt[base + (size_t)(d0 + 3) * SEQ] = f2bf(x3);
  }
}

// --------------------------------------------------- causal flash attention
// v5 = round-5 structure (8 waves x 16 q-rows, KVBLK=32, K+V in LDS,
// double-buffered prefetch, split-KV c0/c1) + slot-major V layout:
// Vls[slot][d-row] 16B chunks -> read quad = l15%8 (2-way, conflict-free),
// replacing round 5's row-major V whose 64B rows were an 8-way conflict
// (the entire 1.85e7 SQ_LDS_BANK_CONFLICT).  P stays in per-wave LDS
// (conflict-free; round 6 showed ds_bpermute costs ~10 conflict-cy each).
__global__ __launch_bounds__(512, 4) void flash(const unsigned short* __restrict__ q,
                                                const unsigned short* __restrict__ k,
                                                const unsigned short* __restrict__ vt,
                                                unsigned short* __restrict__ attn,
                                                unsigned short* __restrict__ opart,
                                                float* __restrict__ ml) {
  extern __shared__ __align__(16) unsigned short lds[];
  unsigned short* Kls = lds;            // [2][32 rows * 256]  2 x 16 KB, XOR-swz
  unsigned short* Vls = lds + 16384;    // [2][4 slots][256 rows] 2 x 16 KB
  unsigned short* Pls = lds + 32768;    // [8][16][40]  10 KB (per-wave)

  const int tid  = threadIdx.x;
  const int lane = tid & 63, wid = tid >> 6;
  const int l15 = lane & 15, lg = lane >> 4;

  const int bid = blockIdx.x;
  const int h = bid & 7, kvh = h >> 2;
  const int idx = bid >> 3;
  const int b  = (idx < 32) ? idx : 63 - idx;
  const int c  = (idx < 32) ? 0 : 1;
  const int t0 = c ? (2 * b + 2) : 0;
  const int t1 = c ? (4 * b + 3) : (2 * b + 1);
  const int qb = b * 128 + wid * 16;

  const unsigned short* kbase = k  + (size_t)kvh * SEQ * 256;
  const unsigned short* vtb   = vt + (size_t)kvh * 256 * SEQ;

  // Q fragments (B-operand of swapped QK: lane l15 = q-row, lg = k-chunk)
  bf16x8 qf[8];
  {
    const unsigned short* qrow = q + ((size_t)(qb + l15) * NHEADS + h) * 256 + lg * 8;
#pragma unroll
    for (int kc = 0; kc < 8; ++kc)
      qf[kc] = *reinterpret_cast<const bf16x8*>(qrow + kc * 32);
  }

  f32x4 o[16];
#pragma unroll
  for (int i = 0; i < 16; ++i) o[i] = f32x4{0.f, 0.f, 0.f, 0.f};
  float m = -1e30f, l = 0.f;

  // stage K (XOR-swizzled rows) + V (slot-major) for kv range [t*32, t*32+31]
  auto stage = [&](int bb, int t) {
    const int kvb = t * 32;
#pragma unroll
    for (int i = 0; i < 2; ++i) {                  // K: 1024 chunks of 16B
      int p = i * 512 + tid;
      int krow = p >> 5, pj = p & 31;
      int j = (pj & ~7) | ((pj ^ krow) & 7);       // involution source swizzle
      async_copy16(kbase + (size_t)(kvb + krow) * 256 + j * 8,
                   Kls + bb * 8192 + p * 8);
    }
#pragma unroll
    for (int i = 0; i < 2; ++i) {                  // V: 1024 chunks, slot-major
      int p = i * 512 + tid;
      int slot = p >> 8, vrow = p & 255;           // LDS chunk = slot*256+vrow
      async_copy16(vtb + (size_t)vrow * SEQ + kvb + slot * 8,
                   Vls + bb * 8192 + p * 8);
    }
  };

  int cur = 0;
  stage(0, t0);
  __syncthreads();                                 // drains vmcnt(0)

  for (int t = t0; t <= t1; ++t) {
    const int kvb = t * 32;
    if (t + 1 <= t1) stage(cur ^ 1, t + 1);        // async prefetch next tile

    if (kvb <= qb + 15) {                          // skip fully-masked waves
      const unsigned short* Kc = Kls + cur * 8192;
      const unsigned short* Vc = Vls + cur * 8192;

      // ---- S^T[kv,q] = K.Q^T : A = K rows (kv), B = Q rows (q)
      f32x4 s[2];
      __builtin_amdgcn_s_setprio(1);
#pragma unroll
      for (int n = 0; n < 2; ++n) {
        f32x4 a = f32x4{0.f, 0.f, 0.f, 0.f};
        const int row = n * 16 + l15;
#pragma unroll
        for (int kc = 0; kc < 8; ++kc) {
          int j  = kc * 4 + lg;
          int pj = (j & ~7) | ((j ^ row) & 7);
          bf16x8 kf = *reinterpret_cast<const bf16x8*>(Kc + (row * 32 + pj) * 8);
          a = __builtin_amdgcn_mfma_f32_16x16x32_bf16(kf, qf[kc], a, 0, 0, 0);
        }
        s[n] = a;
      }
      __builtin_amdgcn_s_setprio(0);

      // causal mask: element (kv,q) masked if kv > q; gate if any kv > min q
      if (kvb + 31 > qb) {
#pragma unroll
        for (int n = 0; n < 2; ++n)
#pragma unroll
          for (int r = 0; r < 4; ++r)
            if (kvb + n * 16 + lg * 4 + r > qb + l15) s[n][r] = -1e30f;
      }

      // ---- online softmax, row q = l15 shared by 4 lanes (lg=0..3)
      float m0 = fmaxf(fmaxf(s[0][0], s[0][1]), fmaxf(s[0][2], s[0][3]));
      float m1 = fmaxf(fmaxf(s[1][0], s[1][1]), fmaxf(s[1][2], s[1][3]));
      float pm = fmaxf(m0, m1);
      pm = fmaxf(pm, __shfl_xor(pm, 16));
      pm = fmaxf(pm, __shfl_xor(pm, 32));

      if (__any(pm > m + 8.0f)) {          // defer-max rescale (THR=8)
        float mnew = fmaxf(m, pm);
        float sc = __expf(m - mnew);
#pragma unroll
        for (int i = 0; i < 16; ++i)
#pragma unroll
          for (int r = 0; r < 4; ++r) o[i][r] *= sc;
        l *= sc;
        m = mnew;
      }

#pragma unroll
      for (int n = 0; n < 2; ++n)
#pragma unroll
        for (int r = 0; r < 4; ++r) s[n][r] = __expf(s[n][r] - m);

      float rs = ((s[0][0] + s[0][1]) + (s[0][2] + s[0][3])) +
                 ((s[1][0] + s[1][1]) + (s[1][2] + s[1][3]));
      rs += __shfl_xor(rs, 16);
      rs += __shfl_xor(rs, 32);
      l += rs;

      // P[q=l15][kv] -> per-wave LDS (kv = n*16 + lg*4 + r), row pad to 40
      unsigned short* Pr = Pls + (wid * 16 + l15) * 40;
#pragma unroll
      for (int n = 0; n < 2; ++n) {
        ushort4 w;
        w.x = f2bf(s[n][0]); w.y = f2bf(s[n][1]);
        w.z = f2bf(s[n][2]); w.w = f2bf(s[n][3]);
        *reinterpret_cast<ushort4*>(Pr + n * 16 + lg * 4) = w;
      }
      asm volatile("s_waitcnt lgkmcnt(0)" ::: "memory");
      __builtin_amdgcn_sched_barrier(0);

      // ---- O^T[d,q] += V^T.P^T : A = V^T rows (d, slot-major), B = P rows
      bf16x8 pb = *reinterpret_cast<const bf16x8*>(Pr + lg * 8);
      __builtin_amdgcn_s_setprio(1);
#pragma unroll
      for (int dt = 0; dt < 16; ++dt) {
        bf16x8 vf = *reinterpret_cast<const bf16x8*>(
            Vc + ((lg << 8) + dt * 16 + l15) * 8);
        o[dt] = __builtin_amdgcn_mfma_f32_16x16x32_bf16(vf, pb, o[dt], 0, 0, 0);
      }
      __builtin_amdgcn_s_setprio(0);
    }

    __syncthreads();                               // drain prefetch + LDS reuse
    cur ^= 1;
  }

  // ---- epilogue: lane holds O^T[d = dt*16+lg*4+r, q = qb+l15], UNNORMALIZED
  const int rid = h * SEQ + qb + l15;
  if (c == 0) {
#pragma unroll
    for (int dt = 0; dt < 16; ++dt) {
      ushort4 w;
      w.x = f2bf(o[dt][0]); w.y = f2bf(o[dt][1]);
      w.z = f2bf(o[dt][2]); w.w = f2bf(o[dt][3]);
      *reinterpret_cast<ushort4*>(
          attn + (size_t)(qb + l15) * HID + h * 256 + dt * 16 + lg * 4) = w;
    }
    if (lg == 0) reinterpret_cast<float2*>(ml)[rid] = float2{m, l};
  } else {
#pragma unroll
    for (int dt = 0; dt < 16; ++dt) {
      ushort4 w;
      w.x = f2bf(o[dt][0]); w.y = f2bf(o[dt][1]);
      w.z = f2bf(o[dt][2]); w.w = f2bf(o[dt][3]);
      *reinterpret_cast<ushort4*>(opart + (size_t)rid * 256 + dt * 16 + lg * 4) = w;
    }
    if (lg == 0) reinterpret_cast<float2*>(ml)[32768 + rid] = float2{m, l};
  }
}

// ----------------------------------------------------- split-KV merge pass
// every q-row has exactly 2 partials: c0 (in attn, unnormalized) + c1 (opart).
__global__ __launch_bounds__(256) void merge(const unsigned short* __restrict__ opart,
                                             const float* __restrict__ ml,
                                             unsigned short* __restrict__ attn) {
  const int wid = threadIdx.x >> 6, lane = threadIdx.x & 63;
  const int rid = blockIdx.x * 4 + wid;           // 0..32767 = h*4096 + s
  const int h = rid >> 12, s = rid & 4095;

  float2 ab0 = reinterpret_cast<const float2*>(ml)[rid];
  float2 ab1 = reinterpret_cast<const float2*>(ml)[32768 + rid];
  float M  = fmaxf(ab0.x, ab1.x);
  float w0 = __expf(ab0.x - M), w1 = __expf(ab1.x - M);
  float invL = 1.0f / (w0 * ab0.y + w1 * ab1.y);
  w0 *= invL; w1 *= invL;

  unsigned short* arow = attn + (size_t)s * HID + h * 256;
  ushort4 a = reinterpret_cast<const ushort4*>(arow)[lane];
  ushort4 bq = reinterpret_cast<const ushort4*>(opart + (size_t)rid * 256)[lane];
  ushort4 o;
  o.x = f2bf(w0 * bf2f(a.x) + w1 * bf2f(bq.x));
  o.y = f2bf(w0 * bf2f(a.y) + w1 * bf2f(bq.y));
  o.z = f2bf(w0 * bf2f(a.z) + w1 * bf2f(bq.z));
  o.w = f2bf(w0 * bf2f(a.w) + w1 * bf2f(bq.w));
  reinterpret_cast<ushort4*>(arow)[lane] = o;
}

// ---------------------------------------------------------------- launcher
extern "C" void kernel_launch(void* const* d_in, const int* in_sizes, int n_in,
                              void* d_out, int out_size, void* d_ws, size_t ws_size,
                              hipStream_t stream) {
  const float* hs   = (const float*)d_in[0];
  const float* cosb = (const float*)d_in[1];
  const float* sinb = (const float*)d_in[2];
  const float* qkvw = (const float*)d_in[3];
  const float* ow   = (const float*)d_in[4];

  char* ws = (char*)d_ws;
  unsigned short* hs_bf   = (unsigned short*)(ws + 0);           // 16 MB (dead after QKV GEMM)
  unsigned short* wqkv_bf = (unsigned short*)(ws + 16777216);    // 12 MB (dead after QKV GEMM)
  unsigned short* wo_bf   = (unsigned short*)(ws + 29360128);    //  8 MB (live till final GEMM)
  unsigned short* qkv_bf  = (unsigned short*)(ws + 37748736);    // 24 MB (dead after postproc)
  unsigned short* attn_bf = qkv_bf;                              // 16 MB overlay
  unsigned short* q_bf    = (unsigned short*)(ws + 62914560);    // 16 MB
  unsigned short* k_bf    = (unsigned short*)(ws + 79691776);    //  4 MB
  unsigned short* vt_bf   = (unsigned short*)(ws + 83886080);    //  4 MB
  // flash partial overlays (regions dead after the QKV GEMM):
  unsigned short* opart   = (unsigned short*)(ws + 0);           // 16 MB (c1 partials)
  float*          mlbuf   = (float*)(ws + 26214400);             // 512 KB (2x32768 float2)

  cvt_bf16<<<dim3((SEQ * HID / 4 + 255) / 256), dim3(256), 0, stream>>>(hs, hs_bf, SEQ * HID / 4);
  cvt_bf16<<<dim3((QKVN * HID / 4 + 255) / 256), dim3(256), 0, stream>>>(qkvw, wqkv_bf, QKVN * HID / 4);
  cvt_bf16<<<dim3((HID * HID / 4 + 255) / 256), dim3(256), 0, stream>>>(ow, wo_bf, HID * HID / 4);

  gemm_bt<true><<<dim3(QKVN / 128, SEQ / 128), dim3(256), 0, stream>>>(
      hs_bf, wqkv_bf, qkv_bf, SEQ, QKVN, HID);

  postproc<<<dim3(SEQ * 12 / 4), dim3(256), 0, stream>>>(qkv_bf, cosb, sinb, q_bf, k_bf, vt_bf);

  flash<<<dim3(512), dim3(512), 75776, stream>>>(q_bf, k_bf, vt_bf, attn_bf, opart, mlbuf);

  merge<<<dim3(8192), dim3(256), 0, stream>>>(opart, mlbuf, attn_bf);

  gemm_bt<false><<<dim3(HID / 128, SEQ / 128), dim3(256), 0, stream>>>(
      attn_bf, wo_bf, d_out, SEQ, HID, HID);
}

// Round 8
// 371.820 us; speedup vs baseline: 1.1365x; 1.1365x over previous
//
#include <hip/hip_runtime.h>

// Problem constants (fixed by the reference)
#define NHEADS 8
#define NKVH   2
#define HD     256
#define SEQ    4096
#define HID    2048
#define QKVN   3072   // (NH + 2*NKV) * D
#define SCAL   (1.0f/256.0f)

typedef __attribute__((ext_vector_type(8))) __bf16 bf16x8;
typedef __attribute__((ext_vector_type(4))) float  f32x4;

__device__ __forceinline__ unsigned short f2bf(float f) {
  unsigned int u = __builtin_bit_cast(unsigned int, f);
  u += 0x7fffu + ((u >> 16) & 1u);          // round-to-nearest-even
  return (unsigned short)(u >> 16);
}
__device__ __forceinline__ float bf2f(unsigned short b) {
  return __builtin_bit_cast(float, (unsigned int)b << 16);
}

// async global->LDS, 16B per lane (linear LDS dest = wave base + lane*16)
__device__ __forceinline__ void async_copy16(const void* g, void* l) {
  __builtin_amdgcn_global_load_lds(
      (__attribute__((address_space(1))) void*)(g),
      (__attribute__((address_space(3))) void*)(l), 16, 0, 0);
}

// ---------------------------------------------------------------- fp32->bf16
__global__ __launch_bounds__(256) void cvt_bf16(const float* __restrict__ in,
                                                unsigned short* __restrict__ out,
                                                int n4) {
  int i = blockIdx.x * 256 + threadIdx.x;
  if (i >= n4) return;
  float4 v = reinterpret_cast<const float4*>(in)[i];
  ushort4 o;
  o.x = f2bf(v.x); o.y = f2bf(v.y); o.z = f2bf(v.z); o.w = f2bf(v.w);
  reinterpret_cast<ushort4*>(out)[i] = o;
}

// ------------------------------------------------------- C = A(M,K) * B(N,K)^T
// 128x128 tile, BK=64, 4 waves as 2x2 of 64x64.  (verified rounds 1-7)
template <bool OUT_BF16>
__global__ __launch_bounds__(256) void gemm_bt(const unsigned short* __restrict__ A,
                                               const unsigned short* __restrict__ B,
                                               void* __restrict__ C,
                                               int M, int N, int K) {
  __shared__ __align__(16) unsigned short Als[128 * 64];
  __shared__ __align__(16) unsigned short Bls[128 * 64];
  const int t    = threadIdx.x;
  const int lane = t & 63;
  const int wid  = t >> 6;
  const int wr = wid >> 1, wc = wid & 1;
  const int l15 = lane & 15, lg = lane >> 4;
  const int m0 = blockIdx.y * 128, n0 = blockIdx.x * 128;

  f32x4 acc[4][4] = {};

  for (int k0 = 0; k0 < K; k0 += 64) {
    __syncthreads();                                  // LDS reuse fence
#pragma unroll
    for (int i = 0; i < 4; ++i) {
      int c   = i * 256 + t;                          // 16B chunk index 0..1023
      int kc  = c >> 9;
      int row = (c >> 2) & 127;
      int j8  = (c & 3) ^ (row & 3);                  // inverse-swizzled source
      int gcol = k0 + kc * 32 + j8 * 8;
      async_copy16(A + (size_t)(m0 + row) * K + gcol, Als + c * 8);
      async_copy16(B + (size_t)(n0 + row) * K + gcol, Bls + c * 8);
    }
    __syncthreads();                                  // drains vmcnt before use
#pragma unroll
    for (int kc = 0; kc < 2; ++kc) {
      bf16x8 af[4], bfr[4];
#pragma unroll
      for (int m = 0; m < 4; ++m) {
        int row   = wr * 64 + m * 16 + l15;
        int chunk = kc * 512 + row * 4 + (lg ^ (row & 3));
        af[m] = *reinterpret_cast<const bf16x8*>(Als + chunk * 8);
      }
#pragma unroll
      for (int n = 0; n < 4; ++n) {
        int row   = wc * 64 + n * 16 + l15;
        int chunk = kc * 512 + row * 4 + (lg ^ (row & 3));
        bfr[n] = *reinterpret_cast<const bf16x8*>(Bls + chunk * 8);
      }
#pragma unroll
      for (int m = 0; m < 4; ++m)
#pragma unroll
        for (int n = 0; n < 4; ++n)
          acc[m][n] = __builtin_amdgcn_mfma_f32_16x16x32_bf16(af[m], bfr[n],
                                                              acc[m][n], 0, 0, 0);
    }
  }

#pragma unroll
  for (int m = 0; m < 4; ++m) {
#pragma unroll
    for (int n = 0; n < 4; ++n) {
      int col = n0 + wc * 64 + n * 16 + l15;
#pragma unroll
      for (int r = 0; r < 4; ++r) {
        int rowg = m0 + wr * 64 + m * 16 + lg * 4 + r;   // C/D: row=(l>>4)*4+r
        if constexpr (OUT_BF16)
          reinterpret_cast<unsigned short*>(C)[(size_t)rowg * N + col] =
              f2bf(acc[m][n][r]);
        else
          reinterpret_cast<float*>(C)[(size_t)rowg * N + col] = acc[m][n][r];
      }
    }
  }
}

// --------------------------------------------- RMSNorm + RoPE + layout split
// v writes now go to a staging-ready tiled layout so the flash V stage is a
// pure linear (coalesced) copy:  vtg[kvh][t=s>>5][slot=(s>>3)&3][d=0..255][s&7]
__global__ __launch_bounds__(256) void postproc(const unsigned short* __restrict__ qkv,
                                                const float* __restrict__ cosb,
                                                const float* __restrict__ sinb,
                                                unsigned short* __restrict__ q,
                                                unsigned short* __restrict__ k,
                                                unsigned short* __restrict__ vt) {
  const int wid = threadIdx.x >> 6, lane = threadIdx.x & 63;
  const int task = blockIdx.x * 4 + wid;          // 0 .. SEQ*12-1
  const int s = task / 12, comp = task % 12;

  ushort4 raw = reinterpret_cast<const ushort4*>(qkv + (size_t)task * 256)[lane];
  float x0 = bf2f(raw.x), x1 = bf2f(raw.y), x2 = bf2f(raw.z), x3 = bf2f(raw.w);

  float ss = x0 * x0 + x1 * x1 + x2 * x2 + x3 * x3;
#pragma unroll
  for (int m = 1; m < 64; m <<= 1) ss += __shfl_xor(ss, m);
  float inv = rsqrtf(ss * (1.0f / 256.0f) + 1e-6f);
  x0 *= inv; x1 *= inv; x2 *= inv; x3 *= inv;

  if (comp < 10) {  // RoPE: lane d-range 4*lane..4*lane+3, partner ±128
    float4 c  = reinterpret_cast<const float4*>(cosb + (size_t)s * 256)[lane];
    float4 sn = reinterpret_cast<const float4*>(sinb + (size_t)s * 256)[lane];
    float p0 = __shfl_xor(x0, 32), p1 = __shfl_xor(x1, 32);
    float p2 = __shfl_xor(x2, 32), p3 = __shfl_xor(x3, 32);
    float sg = (lane < 32) ? -1.0f : 1.0f;       // rotate_half sign
    x0 = x0 * c.x + sg * p0 * sn.x;
    x1 = x1 * c.y + sg * p1 * sn.y;
    x2 = x2 * c.z + sg * p2 * sn.z;
    x3 = x3 * c.w + sg * p3 * sn.w;
  }

  if (comp < 8) {
    ushort4 o;
    o.x = f2bf(x0 * SCAL); o.y = f2bf(x1 * SCAL);
    o.z = f2bf(x2 * SCAL); o.w = f2bf(x3 * SCAL);
    reinterpret_cast<ushort4*>(q + ((size_t)s * NHEADS + comp) * 256)[lane] = o;
  } else if (comp < 10) {
    ushort4 o;
    o.x = f2bf(x0); o.y = f2bf(x1); o.z = f2bf(x2); o.w = f2bf(x3);
    reinterpret_cast<ushort4*>(k + ((size_t)(comp - 8) * SEQ + s) * 256)[lane] = o;
  } else {  // v -> staging-ready tiled layout (16B chunk = 8 kv of one d)
    size_t base = (size_t)(comp - 10) * 1048576 + (size_t)(s >> 5) * 8192 +
                  (size_t)((s >> 3) & 3) * 2048 + (s & 7);
    int d0 = lane * 4;
    vt[base + (size_t)(d0 + 0) * 8] = f2bf(x0);
    vt[base + (size_t)(d0 + 1) * 8] = f2bf(x1);
    vt[base + (size_t)(d0 + 2) * 8] = f2bf(x2);
    vt[base + (size_t)(d0 + 3) * 8] = f2bf(x3);
  }
}

// --------------------------------------------------- causal flash attention
// v6: GQA head-pairing.  4 waves/block; each wave owns 16 q-rows x 2 HEADS
// (h0, h0+1 share the same kvh), so every K/V LDS read feeds 2 MFMAs
// (halved LDS-reads per FLOP vs round 5) while keeping 2 blocks/CU and the
// proven P-LDS roundtrip.  K XOR-swizzled; V slot-major in LDS, staged as a
// pure linear copy from the staging-ready global layout.  Split-KV: q-block
// b (64 rows), chunks c0=[0,b], c1=[b+1,2b+1] (equal length b+1); 512
// blocks; bids bid/bid+256 have complementary length for LPT pairing.
__global__ __launch_bounds__(256, 2) void flash(const unsigned short* __restrict__ q,
                                                const unsigned short* __restrict__ k,
                                                const unsigned short* __restrict__ vtg,
                                                unsigned short* __restrict__ attn,
                                                unsigned short* __restrict__ opart,
                                                float* __restrict__ ml) {
  extern __shared__ __align__(16) unsigned short lds[];
  unsigned short* Kls = lds;            // [2][32*256]  2 x 16 KB, XOR-swz
  unsigned short* Vls = lds + 16384;    // [2][4][256][8] 2 x 16 KB slot-major
  unsigned short* Pls = lds + 32768;    // [4 waves][2 grp][16 q][40]  10 KB

  const int tid  = threadIdx.x;
  const int lane = tid & 63, wid = tid >> 6;
  const int l15 = lane & 15, lg = lane >> 4;

  const int bid = blockIdx.x;
  const int hp = bid & 3;                        // head-pair 0..3
  const int h0 = hp * 2, kvh = hp >> 1;
  const int idx = bid >> 2;                      // 0..127
  const int b  = (idx < 64) ? idx : 127 - idx;
  const int c  = (idx < 64) ? 0 : 1;
  const int t0 = c ? (b + 1) : 0;
  const int t1 = c ? (2 * b + 1) : b;
  const int qb = b * 64 + wid * 16;              // this wave's 16 q-rows

  const unsigned short* kbase  = k   + (size_t)kvh * SEQ * 256;
  const unsigned short* vstage = vtg + (size_t)kvh * 1048576;

  // Q fragments, one per head of the pair (B-operand of swapped QK)
  bf16x8 qf[2][8];
#pragma unroll
  for (int g = 0; g < 2; ++g) {
    const unsigned short* qrow =
        q + ((size_t)(qb + l15) * NHEADS + h0 + g) * 256 + lg * 8;
#pragma unroll
    for (int kc = 0; kc < 8; ++kc)
      qf[g][kc] = *reinterpret_cast<const bf16x8*>(qrow + kc * 32);
  }

  f32x4 o[16][2];
#pragma unroll
  for (int i = 0; i < 16; ++i)
#pragma unroll
    for (int g = 0; g < 2; ++g) o[i][g] = f32x4{0.f, 0.f, 0.f, 0.f};
  float mr0 = -1e30f, lr0 = 0.f, mr1 = -1e30f, lr1 = 0.f;

  // stage K (XOR-swizzled) + V (linear copy of staging-ready tile)
  auto stage = [&](int bb, int t) {
    const int kvb = t * 32;
#pragma unroll
    for (int i = 0; i < 4; ++i) {                // K: 1024 chunks of 16B
      int p = i * 256 + tid;
      int krow = p >> 5, pj = p & 31;
      int j = (pj & ~7) | ((pj ^ krow) & 7);     // involution source swizzle
      async_copy16(kbase + (size_t)(kvb + krow) * 256 + j * 8,
                   Kls + bb * 8192 + p * 8);
    }
    const unsigned short* vsrc = vstage + (size_t)t * 8192;
#pragma unroll
    for (int i = 0; i < 4; ++i) {                // V: 1024 chunks, pure linear
      int p = i * 256 + tid;
      async_copy16(vsrc + p * 8, Vls + bb * 8192 + p * 8);
    }
  };

  int cur = 0;
  stage(0, t0);
  __syncthreads();                               // drains vmcnt(0)

  for (int t = t0; t <= t1; ++t) {
    const int kvb = t * 32;
    if (t + 1 <= t1) stage(cur ^ 1, t + 1);      // async prefetch next tile

    if (kvb <= qb + 15) {                        // skip fully-masked waves
      const unsigned short* Kc = Kls + cur * 8192;
      const unsigned short* Vc = Vls + cur * 8192;

      // ---- S^T[kv,q] = K.Q^T, both heads share each kf read
      f32x4 s[2][2] = {};
      __builtin_amdgcn_s_setprio(1);
#pragma unroll
      for (int n = 0; n < 2; ++n) {
        const int row = n * 16 + l15;
#pragma unroll
        for (int kc = 0; kc < 8; ++kc) {
          int j  = kc * 4 + lg;
          int pj = (j & ~7) | ((j ^ row) & 7);
          bf16x8 kf = *reinterpret_cast<const bf16x8*>(Kc + (row * 32 + pj) * 8);
          s[0][n] = __builtin_amdgcn_mfma_f32_16x16x32_bf16(kf, qf[0][kc], s[0][n], 0, 0, 0);
          s[1][n] = __builtin_amdgcn_mfma_f32_16x16x32_bf16(kf, qf[1][kc], s[1][n], 0, 0, 0);
        }
      }
      __builtin_amdgcn_s_setprio(0);

      // causal mask: same (kv,q) geometry for both heads
      if (kvb + 31 > qb) {
#pragma unroll
        for (int n = 0; n < 2; ++n)
#pragma unroll
          for (int r = 0; r < 4; ++r)
            if (kvb + n * 16 + lg * 4 + r > qb + l15) {
              s[0][n][r] = -1e30f;
              s[1][n][r] = -1e30f;
            }
      }

      // ---- online softmax per head; row q = l15 shared by 4 lanes (lg)
      float pm0 = fmaxf(fmaxf(fmaxf(s[0][0][0], s[0][0][1]), fmaxf(s[0][0][2], s[0][0][3])),
                        fmaxf(fmaxf(s[0][1][0], s[0][1][1]), fmaxf(s[0][1][2], s[0][1][3])));
      float pm1 = fmaxf(fmaxf(fmaxf(s[1][0][0], s[1][0][1]), fmaxf(s[1][0][2], s[1][0][3])),
                        fmaxf(fmaxf(s[1][1][0], s[1][1][1]), fmaxf(s[1][1][2], s[1][1][3])));
      pm0 = fmaxf(pm0, __shfl_xor(pm0, 16));
      pm0 = fmaxf(pm0, __shfl_xor(pm0, 32));
      pm1 = fmaxf(pm1, __shfl_xor(pm1, 16));
      pm1 = fmaxf(pm1, __shfl_xor(pm1, 32));

      if (__any(fmaxf(pm0 - mr0, pm1 - mr1) > 8.0f)) {   // defer-max (THR=8)
        float mn0 = fmaxf(mr0, pm0), mn1 = fmaxf(mr1, pm1);
        float sc0 = __expf(mr0 - mn0), sc1 = __expf(mr1 - mn1);
#pragma unroll
        for (int i = 0; i < 16; ++i)
#pragma unroll
          for (int r = 0; r < 4; ++r) {
            o[i][0][r] *= sc0;
            o[i][1][r] *= sc1;
          }
        lr0 *= sc0; lr1 *= sc1;
        mr0 = mn0;  mr1 = mn1;
      }

#pragma unroll
      for (int n = 0; n < 2; ++n)
#pragma unroll
        for (int r = 0; r < 4; ++r) {
          s[0][n][r] = __expf(s[0][n][r] - mr0);
          s[1][n][r] = __expf(s[1][n][r] - mr1);
        }

      float rs0 = ((s[0][0][0] + s[0][0][1]) + (s[0][0][2] + s[0][0][3])) +
                  ((s[0][1][0] + s[0][1][1]) + (s[0][1][2] + s[0][1][3]));
      float rs1 = ((s[1][0][0] + s[1][0][1]) + (s[1][0][2] + s[1][0][3])) +
                  ((s[1][1][0] + s[1][1][1]) + (s[1][1][2] + s[1][1][3]));
      rs0 += __shfl_xor(rs0, 16); rs0 += __shfl_xor(rs0, 32);
      rs1 += __shfl_xor(rs1, 16); rs1 += __shfl_xor(rs1, 32);
      lr0 += rs0; lr1 += rs1;

      // P[q=l15][kv] per head -> per-wave LDS rows (pad 40)
#pragma unroll
      for (int g = 0; g < 2; ++g) {
        unsigned short* Pr = Pls + ((wid * 2 + g) * 16 + l15) * 40;
#pragma unroll
        for (int n = 0; n < 2; ++n) {
          ushort4 w;
          w.x = f2bf(s[g][n][0]); w.y = f2bf(s[g][n][1]);
          w.z = f2bf(s[g][n][2]); w.w = f2bf(s[g][n][3]);
          *reinterpret_cast<ushort4*>(Pr + n * 16 + lg * 4) = w;
        }
      }
      asm volatile("s_waitcnt lgkmcnt(0)" ::: "memory");
      __builtin_amdgcn_sched_barrier(0);

      // ---- O^T[d,q] += V^T.P^T, both heads share each vf read
      bf16x8 pb0 = *reinterpret_cast<const bf16x8*>(
          Pls + ((wid * 2 + 0) * 16 + l15) * 40 + lg * 8);
      bf16x8 pb1 = *reinterpret_cast<const bf16x8*>(
          Pls + ((wid * 2 + 1) * 16 + l15) * 40 + lg * 8);
      __builtin_amdgcn_s_setprio(1);
#pragma unroll
      for (int dt = 0; dt < 16; ++dt) {
        bf16x8 vf = *reinterpret_cast<const bf16x8*>(
            Vc + ((lg << 8) + dt * 16 + l15) * 8);
        o[dt][0] = __builtin_amdgcn_mfma_f32_16x16x32_bf16(vf, pb0, o[dt][0], 0, 0, 0);
        o[dt][1] = __builtin_amdgcn_mfma_f32_16x16x32_bf16(vf, pb1, o[dt][1], 0, 0, 0);
      }
      __builtin_amdgcn_s_setprio(0);
    }

    __syncthreads();                             // drain prefetch + LDS reuse
    cur ^= 1;
  }

  // ---- epilogue: lane holds O^T[d = dt*16+lg*4+r, q = qb+l15] per head
#pragma unroll
  for (int g = 0; g < 2; ++g) {
    const int head = h0 + g;
    const int qrow = qb + l15;
    const int rid = head * SEQ + qrow;
    const float mg = g ? mr1 : mr0;
    const float lg_ = g ? lr1 : lr0;
    if (c == 0) {
#pragma unroll
      for (int dt = 0; dt < 16; ++dt) {
        ushort4 w;
        w.x = f2bf(o[dt][g][0]); w.y = f2bf(o[dt][g][1]);
        w.z = f2bf(o[dt][g][2]); w.w = f2bf(o[dt][g][3]);
        *reinterpret_cast<ushort4*>(
            attn + (size_t)qrow * HID + head * 256 + dt * 16 + lg * 4) = w;
      }
      if (lg == 0) reinterpret_cast<float2*>(ml)[rid] = float2{mg, lg_};
    } else {
#pragma unroll
      for (int dt = 0; dt < 16; ++dt) {
        ushort4 w;
        w.x = f2bf(o[dt][g][0]); w.y = f2bf(o[dt][g][1]);
        w.z = f2bf(o[dt][g][2]); w.w = f2bf(o[dt][g][3]);
        *reinterpret_cast<ushort4*>(opart + (size_t)rid * 256 + dt * 16 + lg * 4) = w;
      }
      if (lg == 0) reinterpret_cast<float2*>(ml)[32768 + rid] = float2{mg, lg_};
    }
  }
}

// ----------------------------------------------------- split-KV merge pass
// every q-row has exactly 2 partials: c0 (in attn, unnormalized) + c1 (opart).
__global__ __launch_bounds__(256) void merge(const unsigned short* __restrict__ opart,
                                             const float* __restrict__ ml,
                                             unsigned short* __restrict__ attn) {
  const int wid = threadIdx.x >> 6, lane = threadIdx.x & 63;
  const int rid = blockIdx.x * 4 + wid;           // 0..32767 = h*4096 + s
  const int h = rid >> 12, s = rid & 4095;

  float2 ab0 = reinterpret_cast<const float2*>(ml)[rid];
  float2 ab1 = reinterpret_cast<const float2*>(ml)[32768 + rid];
  float M  = fmaxf(ab0.x, ab1.x);
  float w0 = __expf(ab0.x - M), w1 = __expf(ab1.x - M);
  float invL = 1.0f / (w0 * ab0.y + w1 * ab1.y);
  w0 *= invL; w1 *= invL;

  unsigned short* arow = attn + (size_t)s * HID + h * 256;
  ushort4 a = reinterpret_cast<const ushort4*>(arow)[lane];
  ushort4 bq = reinterpret_cast<const ushort4*>(opart + (size_t)rid * 256)[lane];
  ushort4 o;
  o.x = f2bf(w0 * bf2f(a.x) + w1 * bf2f(bq.x));
  o.y = f2bf(w0 * bf2f(a.y) + w1 * bf2f(bq.y));
  o.z = f2bf(w0 * bf2f(a.z) + w1 * bf2f(bq.z));
  o.w = f2bf(w0 * bf2f(a.w) + w1 * bf2f(bq.w));
  reinterpret_cast<ushort4*>(arow)[lane] = o;
}

// ---------------------------------------------------------------- launcher
extern "C" void kernel_launch(void* const* d_in, const int* in_sizes, int n_in,
                              void* d_out, int out_size, void* d_ws, size_t ws_size,
                              hipStream_t stream) {
  const float* hs   = (const float*)d_in[0];
  const float* cosb = (const float*)d_in[1];
  const float* sinb = (const float*)d_in[2];
  const float* qkvw = (const float*)d_in[3];
  const float* ow   = (const float*)d_in[4];

  char* ws = (char*)d_ws;
  unsigned short* hs_bf   = (unsigned short*)(ws + 0);           // 16 MB (dead after QKV GEMM)
  unsigned short* wqkv_bf = (unsigned short*)(ws + 16777216);    // 12 MB (dead after QKV GEMM)
  unsigned short* wo_bf   = (unsigned short*)(ws + 29360128);    //  8 MB (live till final GEMM)
  unsigned short* qkv_bf  = (unsigned short*)(ws + 37748736);    // 24 MB (dead after postproc)
  unsigned short* attn_bf = qkv_bf;                              // 16 MB overlay
  unsigned short* q_bf    = (unsigned short*)(ws + 62914560);    // 16 MB
  unsigned short* k_bf    = (unsigned short*)(ws + 79691776);    //  4 MB
  unsigned short* vt_bf   = (unsigned short*)(ws + 83886080);    //  4 MB (staging-ready layout)
  // flash partial overlays (regions dead after the QKV GEMM):
  unsigned short* opart   = (unsigned short*)(ws + 0);           // 16 MB (c1 partials)
  float*          mlbuf   = (float*)(ws + 26214400);             // 512 KB (2x32768 float2)

  cvt_bf16<<<dim3((SEQ * HID / 4 + 255) / 256), dim3(256), 0, stream>>>(hs, hs_bf, SEQ * HID / 4);
  cvt_bf16<<<dim3((QKVN * HID / 4 + 255) / 256), dim3(256), 0, stream>>>(qkvw, wqkv_bf, QKVN * HID / 4);
  cvt_bf16<<<dim3((HID * HID / 4 + 255) / 256), dim3(256), 0, stream>>>(ow, wo_bf, HID * HID / 4);

  gemm_bt<true><<<dim3(QKVN / 128, SEQ / 128), dim3(256), 0, stream>>>(
      hs_bf, wqkv_bf, qkv_bf, SEQ, QKVN, HID);

  postproc<<<dim3(SEQ * 12 / 4), dim3(256), 0, stream>>>(qkv_bf, cosb, sinb, q_bf, k_bf, vt_bf);

  flash<<<dim3(512), dim3(256), 75776, stream>>>(q_bf, k_bf, vt_bf, attn_bf, opart, mlbuf);

  merge<<<dim3(8192), dim3(256), 0, stream>>>(opart, mlbuf, attn_bf);

  gemm_bt<false><<<dim3(HID / 128, SEQ / 128), dim3(256), 0, stream>>>(
      attn_bf, wo_bf, d_out, SEQ, HID, HID);
}

// Round 9
// 345.440 us; speedup vs baseline: 1.2233x; 1.0764x over previous
//
#include <hip/hip_runtime.h>

// Problem constants (fixed by the reference)
#define NHEADS 8
#define NKVH   2
#define HD     256
#define SEQ    4096
#define HID    2048
#define QKVN   3072   // (NH + 2*NKV) * D
#define SCAL   (1.0f/256.0f)
#define NITEMS 640

typedef __attribute__((ext_vector_type(8))) __bf16 bf16x8;
typedef __attribute__((ext_vector_type(4))) float  f32x4;

__device__ __forceinline__ unsigned short f2bf(float f) {
  unsigned int u = __builtin_bit_cast(unsigned int, f);
  u += 0x7fffu + ((u >> 16) & 1u);          // round-to-nearest-even
  return (unsigned short)(u >> 16);
}
__device__ __forceinline__ float bf2f(unsigned short b) {
  return __builtin_bit_cast(float, (unsigned int)b << 16);
}

// async global->LDS, 16B per lane (linear LDS dest = wave base + lane*16)
__device__ __forceinline__ void async_copy16(const void* g, void* l) {
  __builtin_amdgcn_global_load_lds(
      (__attribute__((address_space(1))) void*)(g),
      (__attribute__((address_space(3))) void*)(l), 16, 0, 0);
}

// partial-slot prefix for q-block b: sum of (n_b'-1) for b' < b,
// n_b = (b>>4)+1  (chunks of 32 tiles)
__device__ __forceinline__ int slot_prefix(int b) {
  if (b < 16) return 0;
  if (b < 32) return b - 16;
  if (b < 48) return 16 + 2 * (b - 32);
  return 48 + 3 * (b - 48);
}

// ---------------------------------------------------------------- fp32->bf16
__global__ __launch_bounds__(256) void cvt_bf16(const float* __restrict__ in,
                                                unsigned short* __restrict__ out,
                                                int n4) {
  int i = blockIdx.x * 256 + threadIdx.x;
  if (i >= n4) return;
  float4 v = reinterpret_cast<const float4*>(in)[i];
  ushort4 o;
  o.x = f2bf(v.x); o.y = f2bf(v.y); o.z = f2bf(v.z); o.w = f2bf(v.w);
  reinterpret_cast<ushort4*>(out)[i] = o;
}

// ------------------------------------------------------- C = A(M,K) * B(N,K)^T
// 128x128 tile, BK=64, 4 waves as 2x2 of 64x64.  (verified rounds 1-8)
template <bool OUT_BF16>
__global__ __launch_bounds__(256) void gemm_bt(const unsigned short* __restrict__ A,
                                               const unsigned short* __restrict__ B,
                                               void* __restrict__ C,
                                               int M, int N, int K) {
  __shared__ __align__(16) unsigned short Als[128 * 64];
  __shared__ __align__(16) unsigned short Bls[128 * 64];
  const int t    = threadIdx.x;
  const int lane = t & 63;
  const int wid  = t >> 6;
  const int wr = wid >> 1, wc = wid & 1;
  const int l15 = lane & 15, lg = lane >> 4;
  const int m0 = blockIdx.y * 128, n0 = blockIdx.x * 128;

  f32x4 acc[4][4] = {};

  for (int k0 = 0; k0 < K; k0 += 64) {
    __syncthreads();                                  // LDS reuse fence
#pragma unroll
    for (int i = 0; i < 4; ++i) {
      int c   = i * 256 + t;                          // 16B chunk index 0..1023
      int kc  = c >> 9;
      int row = (c >> 2) & 127;
      int j8  = (c & 3) ^ (row & 3);                  // inverse-swizzled source
      int gcol = k0 + kc * 32 + j8 * 8;
      async_copy16(A + (size_t)(m0 + row) * K + gcol, Als + c * 8);
      async_copy16(B + (size_t)(n0 + row) * K + gcol, Bls + c * 8);
    }
    __syncthreads();                                  // drains vmcnt before use
#pragma unroll
    for (int kc = 0; kc < 2; ++kc) {
      bf16x8 af[4], bfr[4];
#pragma unroll
      for (int m = 0; m < 4; ++m) {
        int row   = wr * 64 + m * 16 + l15;
        int chunk = kc * 512 + row * 4 + (lg ^ (row & 3));
        af[m] = *reinterpret_cast<const bf16x8*>(Als + chunk * 8);
      }
#pragma unroll
      for (int n = 0; n < 4; ++n) {
        int row   = wc * 64 + n * 16 + l15;
        int chunk = kc * 512 + row * 4 + (lg ^ (row & 3));
        bfr[n] = *reinterpret_cast<const bf16x8*>(Bls + chunk * 8);
      }
#pragma unroll
      for (int m = 0; m < 4; ++m)
#pragma unroll
        for (int n = 0; n < 4; ++n)
          acc[m][n] = __builtin_amdgcn_mfma_f32_16x16x32_bf16(af[m], bfr[n],
                                                              acc[m][n], 0, 0, 0);
    }
  }

#pragma unroll
  for (int m = 0; m < 4; ++m) {
#pragma unroll
    for (int n = 0; n < 4; ++n) {
      int col = n0 + wc * 64 + n * 16 + l15;
#pragma unroll
      for (int r = 0; r < 4; ++r) {
        int rowg = m0 + wr * 64 + m * 16 + lg * 4 + r;   // C/D: row=(l>>4)*4+r
        if constexpr (OUT_BF16)
          reinterpret_cast<unsigned short*>(C)[(size_t)rowg * N + col] =
              f2bf(acc[m][n][r]);
        else
          reinterpret_cast<float*>(C)[(size_t)rowg * N + col] = acc[m][n][r];
      }
    }
  }
}

// --------------------------------------------- RMSNorm + RoPE + layout split
// v -> staging-ready tiled layout: vtg[kvh][t=s>>5][slot=(s>>3)&3][d][s&7]
__global__ __launch_bounds__(256) void postproc(const unsigned short* __restrict__ qkv,
                                                const float* __restrict__ cosb,
                                                const float* __restrict__ sinb,
                                                unsigned short* __restrict__ q,
                                                unsigned short* __restrict__ k,
                                                unsigned short* __restrict__ vt) {
  const int wid = threadIdx.x >> 6, lane = threadIdx.x & 63;
  const int task = blockIdx.x * 4 + wid;          // 0 .. SEQ*12-1
  const int s = task / 12, comp = task % 12;

  ushort4 raw = reinterpret_cast<const ushort4*>(qkv + (size_t)task * 256)[lane];
  float x0 = bf2f(raw.x), x1 = bf2f(raw.y), x2 = bf2f(raw.z), x3 = bf2f(raw.w);

  float ss = x0 * x0 + x1 * x1 + x2 * x2 + x3 * x3;
#pragma unroll
  for (int m = 1; m < 64; m <<= 1) ss += __shfl_xor(ss, m);
  float inv = rsqrtf(ss * (1.0f / 256.0f) + 1e-6f);
  x0 *= inv; x1 *= inv; x2 *= inv; x3 *= inv;

  if (comp < 10) {  // RoPE: lane d-range 4*lane..4*lane+3, partner ±128
    float4 c  = reinterpret_cast<const float4*>(cosb + (size_t)s * 256)[lane];
    float4 sn = reinterpret_cast<const float4*>(sinb + (size_t)s * 256)[lane];
    float p0 = __shfl_xor(x0, 32), p1 = __shfl_xor(x1, 32);
    float p2 = __shfl_xor(x2, 32), p3 = __shfl_xor(x3, 32);
    float sg = (lane < 32) ? -1.0f : 1.0f;       // rotate_half sign
    x0 = x0 * c.x + sg * p0 * sn.x;
    x1 = x1 * c.y + sg * p1 * sn.y;
    x2 = x2 * c.z + sg * p2 * sn.z;
    x3 = x3 * c.w + sg * p3 * sn.w;
  }

  if (comp < 8) {
    ushort4 o;
    o.x = f2bf(x0 * SCAL); o.y = f2bf(x1 * SCAL);
    o.z = f2bf(x2 * SCAL); o.w = f2bf(x3 * SCAL);
    reinterpret_cast<ushort4*>(q + ((size_t)s * NHEADS + comp) * 256)[lane] = o;
  } else if (comp < 10) {
    ushort4 o;
    o.x = f2bf(x0); o.y = f2bf(x1); o.z = f2bf(x2); o.w = f2bf(x3);
    reinterpret_cast<ushort4*>(k + ((size_t)(comp - 8) * SEQ + s) * 256)[lane] = o;
  } else {  // v -> staging-ready tiled layout (16B chunk = 8 kv of one d)
    size_t base = (size_t)(comp - 10) * 1048576 + (size_t)(s >> 5) * 8192 +
                  (size_t)((s >> 3) & 3) * 2048 + (s & 7);
    int d0 = lane * 4;
    vt[base + (size_t)(d0 + 0) * 8] = f2bf(x0);
    vt[base + (size_t)(d0 + 1) * 8] = f2bf(x1);
    vt[base + (size_t)(d0 + 2) * 8] = f2bf(x2);
    vt[base + (size_t)(d0 + 3) * 8] = f2bf(x3);
  }
}

// --------------------------------------------------- causal flash attention
// v7: persistent blocks + dynamic work queue.  512 blocks of 4 waves pull
// items off an atomic ticket; 640 items = (head-pair, q-block b, chunk j)
// with chunks of <=32 KVBLK-32 tiles (n_b = (b>>4)+1 chunks), issued in
// descending-b (LPT) order -> backfilling kills the pairing-imbalance idle
// (round 8: occupancy 11.8%).  Per-item machinery identical to round 8:
// head-paired swapped QK^T, K XOR-swz LDS, V slot-major LDS (linear-staged),
// P-LDS roundtrip, defer-max, dbuf prefetch.  Chunk 0 -> attn (unnorm) +
// ml0; chunk j>=1 -> indexed opart slot; merge combines <=4 partials.
__global__ __launch_bounds__(256, 2) void flash(const unsigned short* __restrict__ q,
                                                const unsigned short* __restrict__ k,
                                                const unsigned short* __restrict__ vtg,
                                                unsigned short* __restrict__ attn,
                                                unsigned short* __restrict__ opart,
                                                float* __restrict__ ml0,
                                                float* __restrict__ mlp,
                                                int* __restrict__ ticket) {
  extern __shared__ __align__(16) unsigned short lds[];
  unsigned short* Kls = lds;            // [2][32*256]  2 x 16 KB, XOR-swz
  unsigned short* Vls = lds + 16384;    // [2][4][256][8] 2 x 16 KB slot-major
  unsigned short* Pls = lds + 32768;    // [4 waves][2 grp][16 q][40]  10 KB
  __shared__ int s_item;

  const int tid  = threadIdx.x;
  const int lane = tid & 63, wid = tid >> 6;
  const int l15 = lane & 15, lg = lane >> 4;

  for (;;) {
    if (tid == 0) s_item = atomicAdd(ticket, 1);
    __syncthreads();
    const int it = s_item;
    __syncthreads();
    if (it >= NITEMS) break;

    // ---- decode item: descending b; per b, 4*n_b items (r = hp*n_b + j)
    int b, hp, j;
    if (it < 256)      { b = 63 - (it >> 4);          int r = it & 15;        hp = r >> 2; j = r & 3; }
    else if (it < 448) { int u = it - 256; b = 47 - u / 12; int r = u % 12;   hp = r / 3;  j = r % 3; }
    else if (it < 576) { int u = it - 448; b = 31 - (u >> 3); int r = u & 7;  hp = r >> 1; j = r & 1; }
    else               { int u = it - 576; b = 15 - (u >> 2); hp = u & 3;     j = 0; }

    const int h0 = hp * 2, kvh = hp >> 1;
    const int total_t = 2 * b + 2;                 // tiles of 32 kv
    const int t0 = j * 32;
    const int t1 = min(t0 + 32, total_t) - 1;
    const int qb = b * 64 + wid * 16;              // this wave's 16 q-rows

    const unsigned short* kbase  = k   + (size_t)kvh * SEQ * 256;
    const unsigned short* vstage = vtg + (size_t)kvh * 1048576;

    // Q fragments, one per head of the pair
    bf16x8 qf[2][8];
#pragma unroll
    for (int g = 0; g < 2; ++g) {
      const unsigned short* qrow =
          q + ((size_t)(qb + l15) * NHEADS + h0 + g) * 256 + lg * 8;
#pragma unroll
      for (int kc = 0; kc < 8; ++kc)
        qf[g][kc] = *reinterpret_cast<const bf16x8*>(qrow + kc * 32);
    }

    f32x4 o[16][2];
#pragma unroll
    for (int i = 0; i < 16; ++i)
#pragma unroll
      for (int g = 0; g < 2; ++g) o[i][g] = f32x4{0.f, 0.f, 0.f, 0.f};
    float mr0 = -1e30f, lr0 = 0.f, mr1 = -1e30f, lr1 = 0.f;

    auto stage = [&](int bb, int t) {
      const int kvb = t * 32;
#pragma unroll
      for (int i = 0; i < 4; ++i) {                // K: 1024 chunks of 16B
        int p = i * 256 + tid;
        int krow = p >> 5, pj = p & 31;
        int jj = (pj & ~7) | ((pj ^ krow) & 7);    // involution source swizzle
        async_copy16(kbase + (size_t)(kvb + krow) * 256 + jj * 8,
                     Kls + bb * 8192 + p * 8);
      }
      const unsigned short* vsrc = vstage + (size_t)t * 8192;
#pragma unroll
      for (int i = 0; i < 4; ++i) {                // V: 1024 chunks, linear
        int p = i * 256 + tid;
        async_copy16(vsrc + p * 8, Vls + bb * 8192 + p * 8);
      }
    };

    int cur = 0;
    stage(0, t0);
    __syncthreads();                               // drains vmcnt(0)

    for (int t = t0; t <= t1; ++t) {
      const int kvb = t * 32;
      if (t + 1 <= t1) stage(cur ^ 1, t + 1);      // async prefetch next tile

      if (kvb <= qb + 15) {                        // skip fully-masked waves
        const unsigned short* Kc = Kls + cur * 8192;
        const unsigned short* Vc = Vls + cur * 8192;

        // ---- S^T[kv,q] = K.Q^T, both heads share each kf read
        f32x4 s[2][2] = {};
        __builtin_amdgcn_s_setprio(1);
#pragma unroll
        for (int n = 0; n < 2; ++n) {
          const int row = n * 16 + l15;
#pragma unroll
          for (int kc = 0; kc < 8; ++kc) {
            int jj = kc * 4 + lg;
            int pj = (jj & ~7) | ((jj ^ row) & 7);
            bf16x8 kf = *reinterpret_cast<const bf16x8*>(Kc + (row * 32 + pj) * 8);
            s[0][n] = __builtin_amdgcn_mfma_f32_16x16x32_bf16(kf, qf[0][kc], s[0][n], 0, 0, 0);
            s[1][n] = __builtin_amdgcn_mfma_f32_16x16x32_bf16(kf, qf[1][kc], s[1][n], 0, 0, 0);
          }
        }
        __builtin_amdgcn_s_setprio(0);

        // causal mask: same (kv,q) geometry for both heads
        if (kvb + 31 > qb) {
#pragma unroll
          for (int n = 0; n < 2; ++n)
#pragma unroll
            for (int r = 0; r < 4; ++r)
              if (kvb + n * 16 + lg * 4 + r > qb + l15) {
                s[0][n][r] = -1e30f;
                s[1][n][r] = -1e30f;
              }
        }

        // ---- online softmax per head; row q = l15 shared by 4 lanes (lg)
        float pm0 = fmaxf(fmaxf(fmaxf(s[0][0][0], s[0][0][1]), fmaxf(s[0][0][2], s[0][0][3])),
                          fmaxf(fmaxf(s[0][1][0], s[0][1][1]), fmaxf(s[0][1][2], s[0][1][3])));
        float pm1 = fmaxf(fmaxf(fmaxf(s[1][0][0], s[1][0][1]), fmaxf(s[1][0][2], s[1][0][3])),
                          fmaxf(fmaxf(s[1][1][0], s[1][1][1]), fmaxf(s[1][1][2], s[1][1][3])));
        pm0 = fmaxf(pm0, __shfl_xor(pm0, 16));
        pm0 = fmaxf(pm0, __shfl_xor(pm0, 32));
        pm1 = fmaxf(pm1, __shfl_xor(pm1, 16));
        pm1 = fmaxf(pm1, __shfl_xor(pm1, 32));

        if (__any(fmaxf(pm0 - mr0, pm1 - mr1) > 8.0f)) {   // defer-max (THR=8)
          float mn0 = fmaxf(mr0, pm0), mn1 = fmaxf(mr1, pm1);
          float sc0 = __expf(mr0 - mn0), sc1 = __expf(mr1 - mn1);
#pragma unroll
          for (int i = 0; i < 16; ++i)
#pragma unroll
            for (int r = 0; r < 4; ++r) {
              o[i][0][r] *= sc0;
              o[i][1][r] *= sc1;
            }
          lr0 *= sc0; lr1 *= sc1;
          mr0 = mn0;  mr1 = mn1;
        }

#pragma unroll
        for (int n = 0; n < 2; ++n)
#pragma unroll
          for (int r = 0; r < 4; ++r) {
            s[0][n][r] = __expf(s[0][n][r] - mr0);
            s[1][n][r] = __expf(s[1][n][r] - mr1);
          }

        float rs0 = ((s[0][0][0] + s[0][0][1]) + (s[0][0][2] + s[0][0][3])) +
                    ((s[0][1][0] + s[0][1][1]) + (s[0][1][2] + s[0][1][3]));
        float rs1 = ((s[1][0][0] + s[1][0][1]) + (s[1][0][2] + s[1][0][3])) +
                    ((s[1][1][0] + s[1][1][1]) + (s[1][1][2] + s[1][1][3]));
        rs0 += __shfl_xor(rs0, 16); rs0 += __shfl_xor(rs0, 32);
        rs1 += __shfl_xor(rs1, 16); rs1 += __shfl_xor(rs1, 32);
        lr0 += rs0; lr1 += rs1;

        // P[q=l15][kv] per head -> per-wave LDS rows (pad 40)
#pragma unroll
        for (int g = 0; g < 2; ++g) {
          unsigned short* Pr = Pls + ((wid * 2 + g) * 16 + l15) * 40;
#pragma unroll
          for (int n = 0; n < 2; ++n) {
            ushort4 w;
            w.x = f2bf(s[g][n][0]); w.y = f2bf(s[g][n][1]);
            w.z = f2bf(s[g][n][2]); w.w = f2bf(s[g][n][3]);
            *reinterpret_cast<ushort4*>(Pr + n * 16 + lg * 4) = w;
          }
        }
        asm volatile("s_waitcnt lgkmcnt(0)" ::: "memory");
        __builtin_amdgcn_sched_barrier(0);

        // ---- O^T[d,q] += V^T.P^T, both heads share each vf read
        bf16x8 pb0 = *reinterpret_cast<const bf16x8*>(
            Pls + ((wid * 2 + 0) * 16 + l15) * 40 + lg * 8);
        bf16x8 pb1 = *reinterpret_cast<const bf16x8*>(
            Pls + ((wid * 2 + 1) * 16 + l15) * 40 + lg * 8);
        __builtin_amdgcn_s_setprio(1);
#pragma unroll
        for (int dt = 0; dt < 16; ++dt) {
          bf16x8 vf = *reinterpret_cast<const bf16x8*>(
              Vc + ((lg << 8) + dt * 16 + l15) * 8);
          o[dt][0] = __builtin_amdgcn_mfma_f32_16x16x32_bf16(vf, pb0, o[dt][0], 0, 0, 0);
          o[dt][1] = __builtin_amdgcn_mfma_f32_16x16x32_bf16(vf, pb1, o[dt][1], 0, 0, 0);
        }
        __builtin_amdgcn_s_setprio(0);
      }

      __syncthreads();                             // drain prefetch + LDS reuse
      cur ^= 1;
    }

    // ---- epilogue: lane holds O^T[d = dt*16+lg*4+r, q = qb+l15] per head
    const int qrow = qb + l15;
#pragma unroll
    for (int g = 0; g < 2; ++g) {
      const int head = h0 + g;
      const float mg = g ? mr1 : mr0;
      const float lg_ = g ? lr1 : lr0;
      if (j == 0) {
#pragma unroll
        for (int dt = 0; dt < 16; ++dt) {
          ushort4 w;
          w.x = f2bf(o[dt][g][0]); w.y = f2bf(o[dt][g][1]);
          w.z = f2bf(o[dt][g][2]); w.w = f2bf(o[dt][g][3]);
          *reinterpret_cast<ushort4*>(
              attn + (size_t)qrow * HID + head * 256 + dt * 16 + lg * 4) = w;
        }
        if (lg == 0)
          reinterpret_cast<float2*>(ml0)[head * SEQ + qrow] = float2{mg, lg_};
      } else {
        const int p = slot_prefix(b) + (j - 1);    // 0..95
        const size_t prow = ((size_t)head * 96 + p) * 64 + (qrow & 63);
#pragma unroll
        for (int dt = 0; dt < 16; ++dt) {
          ushort4 w;
          w.x = f2bf(o[dt][g][0]); w.y = f2bf(o[dt][g][1]);
          w.z = f2bf(o[dt][g][2]); w.w = f2bf(o[dt][g][3]);
          *reinterpret_cast<ushort4*>(opart + prow * 256 + dt * 16 + lg * 4) = w;
        }
        if (lg == 0) reinterpret_cast<float2*>(mlp)[prow] = float2{mg, lg_};
      }
    }
    __syncthreads();                               // item fence (s_item reuse)
  }
}

// ----------------------------------------------------- split-KV merge pass
// row s (q-block b = s>>6) has n = (b>>4)+1 partials: chunk0 in attn/ml0,
// chunks 1..n-1 in opart/mlp at slots prefix(b)+j-1.
__global__ __launch_bounds__(256) void merge(const unsigned short* __restrict__ opart,
                                             const float* __restrict__ ml0,
                                             const float* __restrict__ mlp,
                                             unsigned short* __restrict__ attn) {
  const int wid = threadIdx.x >> 6, lane = threadIdx.x & 63;
  const int rid = blockIdx.x * 4 + wid;           // 0..32767 = h*4096 + s
  const int h = rid >> 12, s = rid & 4095;
  const int b = s >> 6;
  const int n = (b >> 4) + 1;

  float2 m_l[4];
  m_l[0] = reinterpret_cast<const float2*>(ml0)[rid];
  const int pf = slot_prefix(b);
  size_t prow[4];
  for (int jj = 1; jj < n; ++jj) {
    prow[jj] = ((size_t)h * 96 + pf + jj - 1) * 64 + (s & 63);
    m_l[jj] = reinterpret_cast<const float2*>(mlp)[prow[jj]];
  }

  float M = m_l[0].x;
  for (int jj = 1; jj < n; ++jj) M = fmaxf(M, m_l[jj].x);
  float w[4], L = 0.f;
  for (int jj = 0; jj < n; ++jj) {
    w[jj] = __expf(m_l[jj].x - M);
    L += w[jj] * m_l[jj].y;
  }
  float invL = 1.0f / L;
  for (int jj = 0; jj < n; ++jj) w[jj] *= invL;

  unsigned short* arow = attn + (size_t)s * HID + h * 256;
  ushort4 a = reinterpret_cast<const ushort4*>(arow)[lane];
  float acc0 = w[0] * bf2f(a.x), acc1 = w[0] * bf2f(a.y);
  float acc2 = w[0] * bf2f(a.z), acc3 = w[0] * bf2f(a.w);
  for (int jj = 1; jj < n; ++jj) {
    ushort4 bq = reinterpret_cast<const ushort4*>(opart + prow[jj] * 256)[lane];
    acc0 += w[jj] * bf2f(bq.x); acc1 += w[jj] * bf2f(bq.y);
    acc2 += w[jj] * bf2f(bq.z); acc3 += w[jj] * bf2f(bq.w);
  }
  ushort4 o;
  o.x = f2bf(acc0); o.y = f2bf(acc1); o.z = f2bf(acc2); o.w = f2bf(acc3);
  reinterpret_cast<ushort4*>(arow)[lane] = o;
}

// ---------------------------------------------------------------- launcher
extern "C" void kernel_launch(void* const* d_in, const int* in_sizes, int n_in,
                              void* d_out, int out_size, void* d_ws, size_t ws_size,
                              hipStream_t stream) {
  const float* hs   = (const float*)d_in[0];
  const float* cosb = (const float*)d_in[1];
  const float* sinb = (const float*)d_in[2];
  const float* qkvw = (const float*)d_in[3];
  const float* ow   = (const float*)d_in[4];

  char* ws = (char*)d_ws;
  unsigned short* hs_bf   = (unsigned short*)(ws + 0);           // 16 MB (dead after QKV GEMM)
  unsigned short* wqkv_bf = (unsigned short*)(ws + 16777216);    // 12 MB (dead after QKV GEMM)
  unsigned short* wo_bf   = (unsigned short*)(ws + 29360128);    //  8 MB (live till final GEMM)
  unsigned short* qkv_bf  = (unsigned short*)(ws + 37748736);    // 24 MB (dead after postproc)
  unsigned short* attn_bf = qkv_bf;                              // 16 MB overlay
  unsigned short* q_bf    = (unsigned short*)(ws + 62914560);    // 16 MB
  unsigned short* k_bf    = (unsigned short*)(ws + 79691776);    //  4 MB
  unsigned short* vt_bf   = (unsigned short*)(ws + 83886080);    //  4 MB (staging-ready layout)
  // flash partial overlays (regions dead after the QKV GEMM):
  unsigned short* opart   = (unsigned short*)(ws + 0);           // 8h*96*64*512B = 24 MB
  float*          ml0buf  = (float*)(ws + 25165824);             // 256 KB (32768 float2)
  float*          mlpbuf  = (float*)(ws + 25427968);             // 384 KB (49152 float2)
  int*            ticket  = (int*)(ws + 25821184);               // 4 B

  cvt_bf16<<<dim3((SEQ * HID / 4 + 255) / 256), dim3(256), 0, stream>>>(hs, hs_bf, SEQ * HID / 4);
  cvt_bf16<<<dim3((QKVN * HID / 4 + 255) / 256), dim3(256), 0, stream>>>(qkvw, wqkv_bf, QKVN * HID / 4);
  cvt_bf16<<<dim3((HID * HID / 4 + 255) / 256), dim3(256), 0, stream>>>(ow, wo_bf, HID * HID / 4);

  gemm_bt<true><<<dim3(QKVN / 128, SEQ / 128), dim3(256), 0, stream>>>(
      hs_bf, wqkv_bf, qkv_bf, SEQ, QKVN, HID);

  postproc<<<dim3(SEQ * 12 / 4), dim3(256), 0, stream>>>(qkv_bf, cosb, sinb, q_bf, k_bf, vt_bf);

  hipMemsetAsync(ticket, 0, 4, stream);

  flash<<<dim3(512), dim3(256), 75776, stream>>>(q_bf, k_bf, vt_bf, attn_bf,
                                                 opart, ml0buf, mlpbuf, ticket);

  merge<<<dim3(8192), dim3(256), 0, stream>>>(opart, ml0buf, mlpbuf, attn_bf);

  gemm_bt<false><<<dim3(HID / 128, SEQ / 128), dim3(256), 0, stream>>>(
      attn_bf, wo_bf, d_out, SEQ, HID, HID);
}